// Round 11
// baseline (261.178 us; speedup 1.0000x reference)
//
#include <hip/hip_runtime.h>
#include <hip/hip_bf16.h>

// Problem sizes (fixed)
#define BB   16
#define SS   32
#define TKK  128
#define NN   512
#define LPB  4096            // S*TK rows per batch
#define RPB  64              // rows per tile
#define TPB  4               // tiles per persistent block

using bf16x8 = __attribute__((ext_vector_type(8))) __bf16;
using f32x4  = __attribute__((ext_vector_type(4))) float;

__device__ inline unsigned pack_bf16(float a, float b) {
  unsigned ua = __float_as_uint(a);
  unsigned ub = __float_as_uint(b);
  ua = (ua + 0x7FFFu + ((ua >> 16) & 1u)) >> 16;   // RNE
  ub = (ub + 0x7FFFu + ((ub >> 16) & 1u)) >> 16;
  return ua | (ub << 16);
}

__device__ inline float tanh_fast(float x) {
  float e = __expf(2.0f * x);
  return 1.0f - 2.0f * __builtin_amdgcn_rcpf(e + 1.0f);
}

// ---------------------------------------------------------------------------
// k-permuted fragment convention (HW-validated R8-R10): element e of
// lane-group lh holds source k = ks*32 + lh*8 + e. A-frag = 16 contiguous
// bf16 of the row. Wpack f = ks*2048 + mt*64 + lane.
// LDS A tile: [64 rows][64 chunks of 16B], stored chunk s = c ^ (row&7) ^ (c>>3)
// (involution-consistent write/read pair, R10-proven correct).
// ---------------------------------------------------------------------------

// ---------------------------------------------------------------------------
// prep: blocks [0,64): Wpack (direct gather); blocks [64,80): dec_fea.
// ---------------------------------------------------------------------------
__global__ __launch_bounds__(512)
void prep_kernel(const float* __restrict__ W_h, uint4* __restrict__ Wpack,
                 const float* __restrict__ s_t_hat,
                 const float* __restrict__ W_d,
                 const float* __restrict__ b_d,
                 float* __restrict__ decfea) {
  int tid = threadIdx.x;
  if (blockIdx.x < 64) {
    int f    = blockIdx.x * 512 + tid;         // 32768 frag-chunks
    int lane = f & 63;
    int mt   = (f >> 6) & 31;
    int ks   = f >> 11;
    int m    = mt * 16 + (lane & 15);
    int lh   = lane >> 4;
    const float4* wp = reinterpret_cast<const float4*>(W_h);
    float4 a = wp[m * 128 + ks * 8 + lh * 2];
    float4 b = wp[m * 128 + ks * 8 + lh * 2 + 1];
    uint4 o;
    o.x = pack_bf16(a.x, a.y); o.y = pack_bf16(a.z, a.w);
    o.z = pack_bf16(b.x, b.y); o.w = pack_bf16(b.z, b.w);
    Wpack[f] = o;
  } else {
    int idx = (blockIdx.x - 64) * 512 + tid;   // 8192 total
    int b = idx >> 9, m = idx & 511;
    const float4* sp = reinterpret_cast<const float4*>(s_t_hat + b * NN);
    const float4* wp = reinterpret_cast<const float4*>(W_d + m * NN);
    float acc = 0.f;
    #pragma unroll 8
    for (int i = 0; i < NN / 4; ++i) {
      float4 a = sp[i], w = wp[i];
      acc += a.x * w.x + a.y * w.y + a.z * w.z + a.w * w.w;
    }
    decfea[idx] = acc + b_d[m];
  }
}

// ---------------------------------------------------------------------------
// Persistent score kernel: 256 blocks (1/CU) x 512 threads (8 waves),
// 4 tiles of 64 rows each, double-buffered 128 KiB LDS. Stage of tile t+1
// is register-chunked (2 x 32 regs, freed between) and interleaved into
// tile t's ks loop. Wave (wm,wr): 8 m-tiles x 32 rows; acc 64 (AGPR).
// Wave-linear conflict-free LDS writes; swizzled reads.
// ---------------------------------------------------------------------------
__global__ __launch_bounds__(512, 2)
void score_kernel(const float* __restrict__ h,
                  const float* __restrict__ coverage,
                  const float* __restrict__ beta,
                  const float* __restrict__ W_c,
                  const float* __restrict__ v,
                  const uint4* __restrict__ Wpack,
                  const float* __restrict__ decfea,
                  float* __restrict__ weighted) {
  __shared__ __align__(16) uint4 Alds[2][4096];   // 128 KiB
  __shared__ float ep[3][NN];                     // 6 KiB epilogue scalars
  __shared__ float scorebuf[4][RPB];              // 1 KiB
  int tid  = threadIdx.x;
  int lane = tid & 63;
  int w    = tid >> 6;                  // wave 0..7
  int wm   = w & 3;                     // m-split (8 mt each)
  int wr   = w >> 2;                    // row-split (32 rows each)
  int lr   = lane & 15;
  int lh   = lane >> 4;
  int tile0 = blockIdx.x * TPB;
  int bidx  = tile0 >> 6;               // constant per block (4 | 64)

  // epilogue scalars -> LDS (512 threads, 512 elements)
  ep[0][tid] = decfea[bidx * NN + tid];
  ep[1][tid] = W_c[tid];
  ep[2][tid] = v[tid];

  const bf16x8* Bq = reinterpret_cast<const bf16x8*>(Wpack) + lane;

  // per-lane stage constants: write slot j -> row R = j*8 + w, stored chunk
  // position = lane, source chunk c = (lane&56) | ((lane&7)^(R&7)^((lane>>3)&7))
  int chi = lane & 56;
  int clo = (lane & 7) ^ ((lane >> 3) & 7);

  // ---- prologue: full stage of tile0 into buf 0 ----
  {
    const float4* hb = reinterpret_cast<const float4*>(h + (size_t)tile0 * RPB * NN);
    #pragma unroll
    for (int j = 0; j < 8; ++j) {
      int R = j * 8 + w;
      int c = chi | (clo ^ (R & 7));
      float4 a = hb[R * 128 + 2 * c];
      float4 b = hb[R * 128 + 2 * c + 1];
      uint4 o;
      o.x = pack_bf16(a.x, a.y); o.y = pack_bf16(a.z, a.w);
      o.z = pack_bf16(b.x, b.y); o.w = pack_bf16(b.z, b.w);
      Alds[0][R * 64 + lane] = o;
    }
  }
  __syncthreads();

  int arow0 = wr * 32 + lr;
  int arow1 = wr * 32 + 16 + lr;

  #pragma unroll
  for (int t = 0; t < TPB; ++t) {
    const bf16x8* A8 = reinterpret_cast<const bf16x8*>(Alds[t & 1]);
    uint4* nxt = Alds[(t + 1) & 1];
    const bool HAS = (t < TPB - 1);
    const float4* hn = reinterpret_cast<const float4*>(h + (size_t)(tile0 + t + 1) * RPB * NN);

    f32x4 acc[8][2];
    const f32x4 zz = {0.f, 0.f, 0.f, 0.f};
    #pragma unroll
    for (int q = 0; q < 8; ++q) { acc[q][0] = zz; acc[q][1] = zz; }

    float4 sgl[8];

    #pragma unroll
    for (int ks = 0; ks < 16; ++ks) {
      // ---- interleaved stage of tile t+1 (chunked: regs freed between) ----
      if (HAS && (ks == 0 || ks == 8)) {
        const int j0 = (ks == 0) ? 0 : 4;
        #pragma unroll
        for (int j = 0; j < 4; ++j) {
          int R = (j0 + j) * 8 + w;
          int c = chi | (clo ^ (R & 7));
          sgl[2 * j]     = hn[R * 128 + 2 * c];
          sgl[2 * j + 1] = hn[R * 128 + 2 * c + 1];
        }
      }
      if (HAS && (ks == 6 || ks == 14)) {
        const int j0 = (ks == 6) ? 0 : 4;
        #pragma unroll
        for (int j = 0; j < 4; ++j) {
          int R = (j0 + j) * 8 + w;
          float4 a = sgl[2 * j], b = sgl[2 * j + 1];
          uint4 o;
          o.x = pack_bf16(a.x, a.y); o.y = pack_bf16(a.z, a.w);
          o.z = pack_bf16(b.x, b.y); o.w = pack_bf16(b.z, b.w);
          nxt[R * 64 + lane] = o;
        }
      }
      // ---- B frags (transient window; unroll lets scheduler hoist) ----
      bf16x8 bb[8];
      #pragma unroll
      for (int q = 0; q < 8; ++q)
        bb[q] = Bq[(ks * 32 + wm * 8 + q) * 64];
      // ---- A frags (swizzled read; (row&7)==(lr&7) for both rows) ----
      int sc64 = (ks * 4 + lh) ^ (lr & 7) ^ (ks >> 1);
      bf16x8 af0 = A8[arow0 * 64 + sc64];
      bf16x8 af1 = A8[arow1 * 64 + sc64];
      #pragma unroll
      for (int q = 0; q < 8; ++q) {
        acc[q][0] = __builtin_amdgcn_mfma_f32_16x16x32_bf16(af0, bb[q], acc[q][0], 0, 0, 0);
        acc[q][1] = __builtin_amdgcn_mfma_f32_16x16x32_bf16(af1, bb[q], acc[q][1], 0, 0, 0);
      }
    }

    // coverage for this tile (before barrier to hide latency)
    float cvl[2][4];
    #pragma unroll
    for (int jj = 0; jj < 2; ++jj)
      #pragma unroll
      for (int r = 0; r < 4; ++r)
        cvl[jj][r] = coverage[(tile0 + t) * RPB + (2 * wr + jj) * 16 + lh * 4 + r];

    __syncthreads();   // A-reads of tile t done; stage-writes of t+1 visible;
                       // previous tile's scorebuf reads done

    // ---- epilogue ----
    float sc[2][4] = {};
    #pragma unroll
    for (int q = 0; q < 8; ++q) {
      int m = (wm * 8 + q) * 16 + lr;
      float dvm = ep[0][m], wcm = ep[1][m], vvm = ep[2][m];
      #pragma unroll
      for (int jj = 0; jj < 2; ++jj)
        #pragma unroll
        for (int r = 0; r < 4; ++r) {
          float x = acc[q][jj][r] + dvm + cvl[jj][r] * wcm;
          sc[jj][r] += vvm * tanh_fast(x);
        }
    }
    #pragma unroll
    for (int jj = 0; jj < 2; ++jj)
      #pragma unroll
      for (int r = 0; r < 4; ++r) {
        float s = sc[jj][r];
        s += __shfl_xor(s, 1);
        s += __shfl_xor(s, 2);
        s += __shfl_xor(s, 4);
        s += __shfl_xor(s, 8);
        sc[jj][r] = s;
      }
    if (lr == 0) {
      #pragma unroll
      for (int jj = 0; jj < 2; ++jj)
        #pragma unroll
        for (int r = 0; r < 4; ++r)
          scorebuf[wm][(2 * wr + jj) * 16 + lh * 4 + r] = sc[jj][r];
    }
    __syncthreads();
    if (tid < RPB) {
      float total = scorebuf[0][tid] + scorebuf[1][tid] + scorebuf[2][tid] + scorebuf[3][tid];
      int gl = (tile0 + t) * RPB + tid;
      int lb = gl & (LPB - 1);
      int s  = lb >> 7;                 // TK = 128
      weighted[bidx * LPB + lb] = beta[bidx * SS + s] * total;
    }
    // no extra barrier: next tile's post-ks barrier orders scorebuf reuse
  }
}

// ---------------------------------------------------------------------------
// Softmax over 4096 per batch, mask, renormalize; write attn_dist + coverage_new.
// Also zeroes c_t for the following atomic-accumulate kernel.
// ---------------------------------------------------------------------------
__global__ void softmax_kernel(const float* __restrict__ coverage,
                               const float* __restrict__ mask,
                               float* __restrict__ out) {
  int b = blockIdx.x;
  int t = threadIdx.x;
  float* ct   = out;                     // [0, 8192)
  float* attn = out + 8192;              // weighted in, attn_dist out
  float* covn = out + 8192 + 65536;      // coverage_new

  ct[b * NN + t] = 0.f;
  ct[b * NN + 256 + t] = 0.f;

  float wv[16];
  float mx = -1e30f;
  #pragma unroll
  for (int i = 0; i < 16; ++i) {
    wv[i] = attn[b * LPB + i * 256 + t];
    mx = fmaxf(mx, wv[i]);
  }
  __shared__ float redm[4], reds[4];
  mx = fmaxf(mx, __shfl_xor(mx, 1));
  mx = fmaxf(mx, __shfl_xor(mx, 2));
  mx = fmaxf(mx, __shfl_xor(mx, 4));
  mx = fmaxf(mx, __shfl_xor(mx, 8));
  mx = fmaxf(mx, __shfl_xor(mx, 16));
  mx = fmaxf(mx, __shfl_xor(mx, 32));
  if ((t & 63) == 0) redm[t >> 6] = mx;
  __syncthreads();
  mx = fmaxf(fmaxf(redm[0], redm[1]), fmaxf(redm[2], redm[3]));

  float e[16];
  float sum = 0.f;
  #pragma unroll
  for (int i = 0; i < 16; ++i) {
    e[i] = __expf(wv[i] - mx) * mask[b * LPB + i * 256 + t];
    sum += e[i];
  }
  sum += __shfl_xor(sum, 1);
  sum += __shfl_xor(sum, 2);
  sum += __shfl_xor(sum, 4);
  sum += __shfl_xor(sum, 8);
  sum += __shfl_xor(sum, 16);
  sum += __shfl_xor(sum, 32);
  if ((t & 63) == 0) reds[t >> 6] = sum;
  __syncthreads();
  sum = reds[0] + reds[1] + reds[2] + reds[3];
  float inv = 1.0f / sum;
  #pragma unroll
  for (int i = 0; i < 16; ++i) {
    int l = i * 256 + t;
    float a = e[i] * inv;
    attn[b * LPB + l] = a;
    covn[b * LPB + l] = coverage[b * LPB + l] + a;
  }
}

// ---------------------------------------------------------------------------
// c_t[b][n] = sum_l attn[b][l] * h[b][l][n]  (memory-bound, atomic partials)
// ---------------------------------------------------------------------------
__global__ void ct_kernel(const float* __restrict__ h, float* __restrict__ out) {
  int blk   = blockIdx.x;                // 1024
  int b     = blk >> 6;
  int chunk = blk & 63;
  int t     = threadIdx.x;
  const float* attn = out + 8192 + b * LPB + chunk * 64;
  __shared__ float as_[64];
  if (t < 64) as_[t] = attn[t];
  __syncthreads();
  const float* hp = h + (size_t)(b * LPB + chunk * 64) * NN;
  float a0 = 0.f, a1 = 0.f;
  #pragma unroll 4
  for (int r = 0; r < 64; ++r) {
    float2 hv = *reinterpret_cast<const float2*>(hp + r * NN + t * 2);
    float av = as_[r];
    a0 += av * hv.x;
    a1 += av * hv.y;
  }
  atomicAdd(&out[b * NN + t * 2],     a0);
  atomicAdd(&out[b * NN + t * 2 + 1], a1);
}

extern "C" void kernel_launch(void* const* d_in, const int* in_sizes, int n_in,
                              void* d_out, int out_size, void* d_ws, size_t ws_size,
                              hipStream_t stream) {
  const float* s_t_hat  = (const float*)d_in[0];
  const float* h        = (const float*)d_in[1];
  const float* coverage = (const float*)d_in[2];
  const float* mask     = (const float*)d_in[3];
  const float* beta     = (const float*)d_in[4];
  const float* W_h      = (const float*)d_in[5];
  const float* W_c      = (const float*)d_in[6];
  const float* W_d      = (const float*)d_in[7];
  const float* b_d      = (const float*)d_in[8];
  const float* v        = (const float*)d_in[9];
  float* out = (float*)d_out;

  uint4* Wpack    = (uint4*)d_ws;               // 512 KiB
  float* decfea   = out + 8192 + 65536;         // staged in coverage_new region
  float* weighted = out + 8192;                 // staged in attn_dist region

  prep_kernel <<<80, 512, 0, stream>>>(W_h, Wpack, s_t_hat, W_d, b_d, decfea);
  score_kernel<<<256, 512, 0, stream>>>(h, coverage, beta, W_c, v,
                                        Wpack, decfea, weighted);
  softmax_kernel<<<16, 256, 0, stream>>>(coverage, mask, out);
  ct_kernel<<<1024, 256, 0, stream>>>(h, out);
}